// Round 2
// baseline (958.758 us; speedup 1.0000x reference)
//
#include <hip/hip_runtime.h>
#include <stdint.h>

typedef float f32x4 __attribute__((ext_vector_type(4)));
typedef short bf16x8 __attribute__((ext_vector_type(8)));

__device__ __forceinline__ unsigned short f2bf(float f) {
  union { float f; uint32_t u; } v; v.f = f;
  uint32_t r = v.u + 0x7FFFu + ((v.u >> 16) & 1u);
  return (unsigned short)(r >> 16);
}

// ---------- elementwise fp32 -> bf16 ----------
__global__ __launch_bounds__(256) void conv_f2b(const float* __restrict__ in,
                                                unsigned short* __restrict__ out, long n) {
  long i = ((long)blockIdx.x * 256 + threadIdx.x) * 4;
  if (i + 3 < n) {
    float4 f = *(const float4*)(in + i);
    ushort4 o;
    o.x = f2bf(f.x); o.y = f2bf(f.y); o.z = f2bf(f.z); o.w = f2bf(f.w);
    *(ushort4*)(out + i) = o;
  }
}

// ---------- batched tiled transpose fp32 [R,C] -> bf16 [C,R] ----------
__global__ __launch_bounds__(256) void transpose_f2b(const float* __restrict__ in,
                                                     unsigned short* __restrict__ out,
                                                     int R, int C) {
  __shared__ unsigned short tile[32][33];
  long base = (long)blockIdx.z * R * C;
  in += base; out += base;
  int c0 = blockIdx.x * 32, r0 = blockIdx.y * 32;
  int tx = threadIdx.x & 31, ty = threadIdx.x >> 5;  // ty: 0..7
#pragma unroll
  for (int i = 0; i < 32; i += 8)
    tile[ty + i][tx] = f2bf(in[(long)(r0 + ty + i) * C + c0 + tx]);
  __syncthreads();
#pragma unroll
  for (int i = 0; i < 32; i += 8)
    out[(long)(c0 + ty + i) * R + r0 + tx] = tile[tx][ty + i];
}

// ---------- fused bias: bfused[j] = sum_r bph_flat[r]*Wproj[r,j] + bproj[j] ----------
__global__ __launch_bounds__(256) void bias_fuse(const float* __restrict__ bph,
                                                 const float* __restrict__ Wproj,
                                                 const float* __restrict__ bproj,
                                                 float* __restrict__ bfused) {
  int j = blockIdx.x * 256 + threadIdx.x;  // < 768
  int r0 = blockIdx.y * 256;
  float acc = 0.f;
  for (int r = r0; r < r0 + 256; r++)
    acc += bph[r] * Wproj[(long)r * 768 + j];
  if (blockIdx.y == 0) acc += bproj[j];
  atomicAdd(&bfused[j], acc);
}

// ---------- staging helpers (8 elements -> bf16 LDS) ----------
__device__ __forceinline__ void stage8(const unsigned short* __restrict__ g,
                                       unsigned short* __restrict__ s) {
  *(uint4*)s = *(const uint4*)g;
}

// ---------- generic 64x64-tile MFMA GEMM: C = A[M,K] @ Bt[N,K]^T ----------
template <typename AT, typename Epi>
__global__ __launch_bounds__(256) void gemm_bt(const AT* __restrict__ A, long asb, int lda,
                                               const unsigned short* __restrict__ Bt, long bsb,
                                               int ldb, int K, Epi epi) {
  __shared__ __align__(16) unsigned short As[64][32];
  __shared__ __align__(16) unsigned short Bs[64][32];
  const int tid = threadIdx.x;
  const int row = tid >> 2;         // 0..63
  const int kc = (tid & 3) * 8;     // 0,8,16,24
  const int lane = tid & 63;
  const int w = tid >> 6;           // wave 0..3
  const int quad = lane >> 4, lr = lane & 15;
  const int bz = blockIdx.z;

  f32x4 acc[4];
#pragma unroll
  for (int i = 0; i < 4; i++) acc[i] = (f32x4){0.f, 0.f, 0.f, 0.f};

  const AT* Ab = A + (long)bz * asb + (long)(blockIdx.y * 64 + row) * lda;
  const unsigned short* Bb = Bt + (long)bz * bsb + (long)(blockIdx.x * 64 + row) * ldb;

  for (int k0 = 0; k0 < K; k0 += 32) {
    stage8(Ab + k0 + kc, &As[row][kc]);
    stage8(Bb + k0 + kc, &Bs[row][kc]);
    __syncthreads();
    bf16x8 a = *(const bf16x8*)&As[w * 16 + lr][quad * 8];
#pragma unroll
    for (int nt = 0; nt < 4; nt++) {
      bf16x8 b = *(const bf16x8*)&Bs[nt * 16 + lr][quad * 8];
      acc[nt] = __builtin_amdgcn_mfma_f32_16x16x32_bf16(a, b, acc[nt], 0, 0, 0);
    }
    __syncthreads();
  }
  const int mg = blockIdx.y * 64 + w * 16 + quad * 4;
  const int ng = blockIdx.x * 64 + lr;
#pragma unroll
  for (int nt = 0; nt < 4; nt++)
#pragma unroll
    for (int r = 0; r < 4; r++)
      epi(bz, mg + r, ng + nt * 16, acc[nt][r]);
}

// ---------- epilogues ----------
struct EpiQKV {  // n = h*192 + d3; scatter to q,k (row-major [BH,T,D]) and v^T ([BH,D,T])
  const float* bqkv;
  unsigned short *q, *k, *vt;
  __device__ void operator()(int, int m, int n, float val) const {
    int h = n / 192, d3 = n - h * 192;
    unsigned short bv = f2bf(val + bqkv[n]);
    int b = m >> 9, t = m & 511;
    long bh = b * 12 + h;
    if (d3 < 64)        q[(bh * 512 + t) * 64 + d3] = bv;
    else if (d3 < 128)  k[(bh * 512 + t) * 64 + (d3 - 64)] = bv;
    else                vt[(bh * 64 + (d3 - 128)) * 512 + t] = bv;
  }
};
struct EpiWf {  // Wfused^T bf16 [768 j, 768 hd]; z = h, m = d
  unsigned short* wft;
  __device__ void operator()(int z, int m, int n, float val) const {
    wft[(long)n * 768 + z * 64 + m] = f2bf(val);
  }
};
struct EpiOut {  // final fp32 output + fused bias
  float* out;
  const float* bfused;
  __device__ void operator()(int, int m, int n, float val) const {
    out[(long)m * 768 + n] = val + bfused[n];
  }
};

// ---------- fused attention: scores + softmax + PV, one (b,h) x 64-row q-tile / block ----
// grid (8 qtiles, 384 bh), 256 threads (4 waves). Each wave owns 16 q-rows.
// Phase 1: S[16,512] = Q K^T in registers (32 f32x4 acc), Q/K frags straight from global.
// Phase 2: row-softmax (cols are lane-local: col = lr + 16*nt, row = quad*4+r),
//          write fp32 probs (required output) + bf16 P into XOR-swizzled LDS.
// Phase 3: PV with A-frags from LDS, V^T frags straight from global (L2-resident).
__global__ __launch_bounds__(256, 2) void attn_fused(
    const unsigned short* __restrict__ q,   // [BH,512,64] bf16
    const unsigned short* __restrict__ k,   // [BH,512,64] bf16
    const unsigned short* __restrict__ vt,  // [BH,64,512] bf16
    float* __restrict__ probs,              // [BH,512,512] fp32 (d_out region)
    unsigned short* __restrict__ sa)        // [B*T,768] bf16
{
  __shared__ __align__(16) unsigned short P[64][512];  // 64 KB, swizzled
  const int tid = threadIdx.x;
  const int w = tid >> 6;
  const int lane = tid & 63;
  const int quad = lane >> 4, lr = lane & 15;
  const int bh = blockIdx.y;
  const int q0 = blockIdx.x * 64;

  const unsigned short* Qb = q + ((long)bh * 512 + q0 + w * 16) * 64;
  const unsigned short* Kb = k + (long)bh * 512 * 64;
  const unsigned short* Vb = vt + (long)bh * 64 * 512;

  // ---- phase 1: scores ----
  bf16x8 a0 = *(const bf16x8*)(Qb + (long)lr * 64 + quad * 8);
  bf16x8 a1 = *(const bf16x8*)(Qb + (long)lr * 64 + quad * 8 + 32);
  f32x4 acc[32];
#pragma unroll
  for (int nt = 0; nt < 32; nt++) acc[nt] = (f32x4){0.f, 0.f, 0.f, 0.f};
#pragma unroll
  for (int nt = 0; nt < 32; nt++) {
    const unsigned short* kr = Kb + (long)(nt * 16 + lr) * 64 + quad * 8;
    bf16x8 b0 = *(const bf16x8*)kr;
    bf16x8 b1 = *(const bf16x8*)(kr + 32);
    acc[nt] = __builtin_amdgcn_mfma_f32_16x16x32_bf16(a0, b0, acc[nt], 0, 0, 0);
    acc[nt] = __builtin_amdgcn_mfma_f32_16x16x32_bf16(a1, b1, acc[nt], 0, 0, 0);
  }

  // ---- phase 2: softmax over s (cols live in the 16 lanes of this quad) ----
  float mx[4], sum[4];
#pragma unroll
  for (int r = 0; r < 4; r++) {
    float m = -1e30f;
#pragma unroll
    for (int nt = 0; nt < 32; nt++) m = fmaxf(m, acc[nt][r]);
#pragma unroll
    for (int off = 8; off; off >>= 1) m = fmaxf(m, __shfl_xor(m, off, 64));
    mx[r] = m;
    sum[r] = 0.f;
  }
#pragma unroll
  for (int nt = 0; nt < 32; nt++)
#pragma unroll
    for (int r = 0; r < 4; r++) {
      float p = __expf(0.125f * (acc[nt][r] - mx[r]));
      acc[nt][r] = p;
      sum[r] += p;
    }
#pragma unroll
  for (int r = 0; r < 4; r++) {
    float s = sum[r];
#pragma unroll
    for (int off = 8; off; off >>= 1) s += __shfl_xor(s, off, 64);
    sum[r] = 1.0f / s;
  }
  // write fp32 probs (required output) + bf16 P into swizzled LDS
  float* Pr = probs + ((long)bh * 512 + q0 + w * 16 + quad * 4) * 512 + lr;
  const int mbase = w * 16 + quad * 4;
#pragma unroll
  for (int nt = 0; nt < 32; nt++)
#pragma unroll
    for (int r = 0; r < 4; r++) {
      float p = acc[nt][r] * sum[r];
      Pr[(long)r * 512 + nt * 16] = p;
      int m = mbase + r;
      int byte = m * 1024 + (((lr + nt * 16) * 2) ^ (((m ^ (m >> 3)) & 7) << 4));
      *(unsigned short*)((char*)P + byte) = f2bf(p);
    }
  __syncthreads();

  // ---- phase 3: PV ----
  f32x4 o[4];
#pragma unroll
  for (int dt = 0; dt < 4; dt++) o[dt] = (f32x4){0.f, 0.f, 0.f, 0.f};
  const int mrow = w * 16 + lr;
  const int swz = ((mrow ^ (mrow >> 3)) & 7) << 4;
#pragma unroll
  for (int ks = 0; ks < 16; ks++) {
    bf16x8 pa = *(const bf16x8*)((char*)P + mrow * 1024 + ((quad * 16 + ks * 64) ^ swz));
#pragma unroll
    for (int dt = 0; dt < 4; dt++) {
      bf16x8 vb = *(const bf16x8*)(Vb + (long)(dt * 16 + lr) * 512 + quad * 8 + ks * 32);
      o[dt] = __builtin_amdgcn_mfma_f32_16x16x32_bf16(pa, vb, o[dt], 0, 0, 0);
    }
  }
  const int b = bh / 12, h = bh - b * 12;
  unsigned short* So = sa + ((long)(b * 512 + q0 + w * 16 + quad * 4)) * 768 + h * 64;
#pragma unroll
  for (int dt = 0; dt < 4; dt++)
#pragma unroll
    for (int r = 0; r < 4; r++)
      So[(long)r * 768 + dt * 16 + lr] = f2bf(o[dt][r]);
}

extern "C" void kernel_launch(void* const* d_in, const int* in_sizes, int n_in,
                              void* d_out, int out_size, void* d_ws, size_t ws_size,
                              hipStream_t stream) {
  const float* x     = (const float*)d_in[0];
  const float* Wqkv  = (const float*)d_in[1];
  const float* bqkv  = (const float*)d_in[2];
  const float* Wph   = (const float*)d_in[3];
  const float* bph   = (const float*)d_in[4];
  const float* Wproj = (const float*)d_in[5];
  const float* bproj = (const float*)d_in[6];
  float* out = (float*)d_out;
  float* probs = out + 12582912L;  // [32,12,512,512]

  char* ws = (char*)d_ws;
  auto alloc = [&](size_t bytes) {
    char* p = ws;
    ws += (bytes + 255) & ~(size_t)255;
    return p;
  };
  unsigned short* x_b    = (unsigned short*)alloc(16384L * 768 * 2);
  unsigned short* wqkvt  = (unsigned short*)alloc(2304L * 768 * 2);
  unsigned short* wph_b  = (unsigned short*)alloc(768L * 768 * 2);
  unsigned short* wprojt = (unsigned short*)alloc(768L * 9216 * 2);
  unsigned short* wft    = (unsigned short*)alloc(768L * 768 * 2);
  float*          bfused = (float*)alloc(768 * 4);
  unsigned short* qb     = (unsigned short*)alloc(12582912L * 2);
  unsigned short* kb     = (unsigned short*)alloc(12582912L * 2);
  unsigned short* vtb    = (unsigned short*)alloc(12582912L * 2);
  unsigned short* sa     = (unsigned short*)alloc(12582912L * 2);

  hipMemsetAsync(bfused, 0, 768 * 4, stream);

  // pack/convert
  conv_f2b<<<12288, 256, 0, stream>>>(x, x_b, 12582912L);
  conv_f2b<<<576, 256, 0, stream>>>(Wph, wph_b, 589824L);
  transpose_f2b<<<dim3(6, 24, 12), 256, 0, stream>>>(Wqkv, wqkvt, 768, 192);
  transpose_f2b<<<dim3(24, 288, 1), 256, 0, stream>>>(Wproj, wprojt, 9216, 768);
  bias_fuse<<<dim3(3, 36), 256, 0, stream>>>(bph, Wproj, bproj, bfused);

  // QKV projection: [16384,768] @ [2304,768]^T, scatter epilogue
  gemm_bt<<<dim3(36, 256, 1), 256, 0, stream>>>(x_b, 0L, 768, wqkvt, 0L, 768, 768,
                                                EpiQKV{bqkv, qb, kb, vtb});
  // fused attention: scores + softmax + PV (probs written once, straight to d_out)
  attn_fused<<<dim3(8, 384), 256, 0, stream>>>(qb, kb, vtb, probs, sa);
  // Wfused^T: per h: Wph_h[64,768] @ Wproj_t[:, h*768:+768]^T
  gemm_bt<<<dim3(12, 1, 12), 256, 0, stream>>>(wph_b, 49152L, 768, wprojt, 768L, 9216, 768,
                                               EpiWf{wft});
  // final: [16384,768] @ [768,768]^T + bfused -> d_out
  gemm_bt<<<dim3(12, 256, 1), 256, 0, stream>>>(sa, 0L, 768, wft, 0L, 768, 768,
                                                EpiOut{out, bfused});
}

// Round 3
// 901.590 us; speedup vs baseline: 1.0634x; 1.0634x over previous
//
#include <hip/hip_runtime.h>
#include <stdint.h>

typedef float f32x4 __attribute__((ext_vector_type(4)));
typedef short bf16x8 __attribute__((ext_vector_type(8)));

__device__ __forceinline__ unsigned short f2bf(float f) {
  union { float f; uint32_t u; } v; v.f = f;
  uint32_t r = v.u + 0x7FFFu + ((v.u >> 16) & 1u);
  return (unsigned short)(r >> 16);
}

// async global->LDS, 16B per lane. LDS dest is wave-uniform base + lane*16.
__device__ __forceinline__ void gload16(const unsigned short* g, unsigned short* l) {
  __builtin_amdgcn_global_load_lds(
      (const __attribute__((address_space(1))) void*)g,
      (__attribute__((address_space(3))) void*)l, 16, 0, 0);
}

// ---------- elementwise fp32 -> bf16 ----------
__global__ __launch_bounds__(256) void conv_f2b(const float* __restrict__ in,
                                                unsigned short* __restrict__ out, long n) {
  long i = ((long)blockIdx.x * 256 + threadIdx.x) * 4;
  if (i + 3 < n) {
    float4 f = *(const float4*)(in + i);
    ushort4 o;
    o.x = f2bf(f.x); o.y = f2bf(f.y); o.z = f2bf(f.z); o.w = f2bf(f.w);
    *(ushort4*)(out + i) = o;
  }
}

// ---------- batched tiled transpose fp32 [R,C] -> bf16 [C,R] ----------
__global__ __launch_bounds__(256) void transpose_f2b(const float* __restrict__ in,
                                                     unsigned short* __restrict__ out,
                                                     int R, int C) {
  __shared__ unsigned short tile[32][33];
  long base = (long)blockIdx.z * R * C;
  in += base; out += base;
  int c0 = blockIdx.x * 32, r0 = blockIdx.y * 32;
  int tx = threadIdx.x & 31, ty = threadIdx.x >> 5;  // ty: 0..7
#pragma unroll
  for (int i = 0; i < 32; i += 8)
    tile[ty + i][tx] = f2bf(in[(long)(r0 + ty + i) * C + c0 + tx]);
  __syncthreads();
#pragma unroll
  for (int i = 0; i < 32; i += 8)
    out[(long)(c0 + ty + i) * R + r0 + tx] = tile[tx][ty + i];
}

// ---------- fused bias: bfused[j] = sum_r bph_flat[r]*Wproj[r,j] + bproj[j] ----------
__global__ __launch_bounds__(256) void bias_fuse(const float* __restrict__ bph,
                                                 const float* __restrict__ Wproj,
                                                 const float* __restrict__ bproj,
                                                 float* __restrict__ bfused) {
  int j = blockIdx.x * 256 + threadIdx.x;  // < 768
  int r0 = blockIdx.y * 256;
  float acc = 0.f;
  for (int r = r0; r < r0 + 256; r++)
    acc += bph[r] * Wproj[(long)r * 768 + j];
  if (blockIdx.y == 0) acc += bproj[j];
  atomicAdd(&bfused[j], acc);
}

// ---------- staging helpers (8 elements -> bf16 LDS) ----------
__device__ __forceinline__ void stage8(const unsigned short* __restrict__ g,
                                       unsigned short* __restrict__ s) {
  *(uint4*)s = *(const uint4*)g;
}

// ---------- generic 64x64-tile MFMA GEMM: C = A[M,K] @ Bt[N,K]^T (small shapes) ------
template <typename AT, typename Epi>
__global__ __launch_bounds__(256) void gemm_bt(const AT* __restrict__ A, long asb, int lda,
                                               const unsigned short* __restrict__ Bt, long bsb,
                                               int ldb, int K, Epi epi) {
  __shared__ __align__(16) unsigned short As[64][32];
  __shared__ __align__(16) unsigned short Bs[64][32];
  const int tid = threadIdx.x;
  const int row = tid >> 2;         // 0..63
  const int kc = (tid & 3) * 8;     // 0,8,16,24
  const int lane = tid & 63;
  const int w = tid >> 6;           // wave 0..3
  const int quad = lane >> 4, lr = lane & 15;
  const int bz = blockIdx.z;

  f32x4 acc[4];
#pragma unroll
  for (int i = 0; i < 4; i++) acc[i] = (f32x4){0.f, 0.f, 0.f, 0.f};

  const AT* Ab = A + (long)bz * asb + (long)(blockIdx.y * 64 + row) * lda;
  const unsigned short* Bb = Bt + (long)bz * bsb + (long)(blockIdx.x * 64 + row) * ldb;

  for (int k0 = 0; k0 < K; k0 += 32) {
    stage8(Ab + k0 + kc, &As[row][kc]);
    stage8(Bb + k0 + kc, &Bs[row][kc]);
    __syncthreads();
    bf16x8 a = *(const bf16x8*)&As[w * 16 + lr][quad * 8];
#pragma unroll
    for (int nt = 0; nt < 4; nt++) {
      bf16x8 b = *(const bf16x8*)&Bs[nt * 16 + lr][quad * 8];
      acc[nt] = __builtin_amdgcn_mfma_f32_16x16x32_bf16(a, b, acc[nt], 0, 0, 0);
    }
    __syncthreads();
  }
  const int mg = blockIdx.y * 64 + w * 16 + quad * 4;
  const int ng = blockIdx.x * 64 + lr;
#pragma unroll
  for (int nt = 0; nt < 4; nt++)
#pragma unroll
    for (int r = 0; r < 4; r++)
      epi(bz, mg + r, ng + nt * 16, acc[nt][r]);
}

// ---------- 128x128-tile MFMA GEMM (ladder step-3 structure): C = A[M,K] @ Bt[N,K]^T --
// 256 threads / 4 waves; each wave owns a 64x64 quadrant (4x4 fragments of 16x16x32).
// Staging via global_load_lds dwordx4 (linear LDS, wave-uniform base + lane*16).
template <typename Epi>
__global__ __launch_bounds__(256) void gemm128(const unsigned short* __restrict__ A, int lda,
                                               const unsigned short* __restrict__ Bt, int ldb,
                                               int K, Epi epi) {
  __shared__ __align__(16) unsigned short As[128][32];
  __shared__ __align__(16) unsigned short Bs[128][32];
  const int tid = threadIdx.x;
  const int lane = tid & 63;
  const int w = tid >> 6;             // wave 0..3
  const int quad = lane >> 4, lr = lane & 15;
  const int sr = lane >> 2;           // staging row within 16-row group
  const int sc = (lane & 3) * 8;      // staging k-offset (elements)

  f32x4 acc[4][4];
#pragma unroll
  for (int i = 0; i < 4; i++)
#pragma unroll
    for (int j = 0; j < 4; j++) acc[i][j] = (f32x4){0.f, 0.f, 0.f, 0.f};

  const unsigned short* Ag = A + (long)(blockIdx.y * 128 + w * 16 + sr) * lda + sc;
  const unsigned short* Bg = Bt + (long)(blockIdx.x * 128 + w * 16 + sr) * ldb + sc;
  unsigned short* Al0 = &As[w * 16][0];
  unsigned short* Al1 = &As[64 + w * 16][0];
  unsigned short* Bl0 = &Bs[w * 16][0];
  unsigned short* Bl1 = &Bs[64 + w * 16][0];
  const int wr = (w >> 1) * 64, wc = (w & 1) * 64;

  for (int k0 = 0; k0 < K; k0 += 32) {
    gload16(Ag + k0, Al0);
    gload16(Ag + k0 + (long)64 * lda, Al1);
    gload16(Bg + k0, Bl0);
    gload16(Bg + k0 + (long)64 * ldb, Bl1);
    __syncthreads();  // drains vmcnt (gload_lds) + barrier
    bf16x8 a[4], b[4];
#pragma unroll
    for (int mt = 0; mt < 4; mt++) a[mt] = *(const bf16x8*)&As[wr + mt * 16 + lr][quad * 8];
#pragma unroll
    for (int nt = 0; nt < 4; nt++) b[nt] = *(const bf16x8*)&Bs[wc + nt * 16 + lr][quad * 8];
#pragma unroll
    for (int mt = 0; mt < 4; mt++)
#pragma unroll
      for (int nt = 0; nt < 4; nt++)
        acc[mt][nt] = __builtin_amdgcn_mfma_f32_16x16x32_bf16(a[mt], b[nt], acc[mt][nt], 0, 0, 0);
    __syncthreads();
  }
  const int mg0 = blockIdx.y * 128 + wr + quad * 4;
  const int ng0 = blockIdx.x * 128 + wc + lr;
#pragma unroll
  for (int mt = 0; mt < 4; mt++)
#pragma unroll
    for (int nt = 0; nt < 4; nt++)
#pragma unroll
      for (int r = 0; r < 4; r++)
        epi(0, mg0 + mt * 16 + r, ng0 + nt * 16, acc[mt][nt][r]);
}

// ---------- epilogues ----------
struct EpiQKV {  // n = h*192 + d3; scatter to q,k (row-major [BH,T,D]) and v^T ([BH,D,T])
  const float* bqkv;
  unsigned short *q, *k, *vt;
  __device__ void operator()(int, int m, int n, float val) const {
    int h = n / 192, d3 = n - h * 192;
    unsigned short bv = f2bf(val + bqkv[n]);
    int b = m >> 9, t = m & 511;
    long bh = b * 12 + h;
    if (d3 < 64)        q[(bh * 512 + t) * 64 + d3] = bv;
    else if (d3 < 128)  k[(bh * 512 + t) * 64 + (d3 - 64)] = bv;
    else                vt[(bh * 64 + (d3 - 128)) * 512 + t] = bv;
  }
};
struct EpiWf {  // Wfused^T bf16 [768 j, 768 hd]; z = h, m = d
  unsigned short* wft;
  __device__ void operator()(int z, int m, int n, float val) const {
    wft[(long)n * 768 + z * 64 + m] = f2bf(val);
  }
};
struct EpiOut {  // final fp32 output + fused bias
  float* out;
  const float* bfused;
  __device__ void operator()(int, int m, int n, float val) const {
    out[(long)m * 768 + n] = val + bfused[n];
  }
};

// ---------- fused attention: scores + softmax + PV, one (b,h) x 64-row q-tile / block ----
__global__ __launch_bounds__(256, 2) void attn_fused(
    const unsigned short* __restrict__ q,   // [BH,512,64] bf16
    const unsigned short* __restrict__ k,   // [BH,512,64] bf16
    const unsigned short* __restrict__ vt,  // [BH,64,512] bf16
    float* __restrict__ probs,              // [BH,512,512] fp32 (d_out region)
    unsigned short* __restrict__ sa)        // [B*T,768] bf16
{
  __shared__ __align__(16) unsigned short P[64][512];  // 64 KB, swizzled
  const int tid = threadIdx.x;
  const int w = tid >> 6;
  const int lane = tid & 63;
  const int quad = lane >> 4, lr = lane & 15;
  const int bh = blockIdx.y;
  const int q0 = blockIdx.x * 64;

  const unsigned short* Qb = q + ((long)bh * 512 + q0 + w * 16) * 64;
  const unsigned short* Kb = k + (long)bh * 512 * 64;
  const unsigned short* Vb = vt + (long)bh * 64 * 512;

  // ---- phase 1: scores ----
  bf16x8 a0 = *(const bf16x8*)(Qb + (long)lr * 64 + quad * 8);
  bf16x8 a1 = *(const bf16x8*)(Qb + (long)lr * 64 + quad * 8 + 32);
  f32x4 acc[32];
#pragma unroll
  for (int nt = 0; nt < 32; nt++) acc[nt] = (f32x4){0.f, 0.f, 0.f, 0.f};
#pragma unroll
  for (int nt = 0; nt < 32; nt++) {
    const unsigned short* kr = Kb + (long)(nt * 16 + lr) * 64 + quad * 8;
    bf16x8 b0 = *(const bf16x8*)kr;
    bf16x8 b1 = *(const bf16x8*)(kr + 32);
    acc[nt] = __builtin_amdgcn_mfma_f32_16x16x32_bf16(a0, b0, acc[nt], 0, 0, 0);
    acc[nt] = __builtin_amdgcn_mfma_f32_16x16x32_bf16(a1, b1, acc[nt], 0, 0, 0);
  }

  // ---- phase 2: softmax over s (cols live in the 16 lanes of this quad) ----
  float mx[4], sum[4];
#pragma unroll
  for (int r = 0; r < 4; r++) {
    float m = -1e30f;
#pragma unroll
    for (int nt = 0; nt < 32; nt++) m = fmaxf(m, acc[nt][r]);
#pragma unroll
    for (int off = 8; off; off >>= 1) m = fmaxf(m, __shfl_xor(m, off, 64));
    mx[r] = m;
    sum[r] = 0.f;
  }
#pragma unroll
  for (int nt = 0; nt < 32; nt++)
#pragma unroll
    for (int r = 0; r < 4; r++) {
      float p = __expf(0.125f * (acc[nt][r] - mx[r]));
      acc[nt][r] = p;
      sum[r] += p;
    }
#pragma unroll
  for (int r = 0; r < 4; r++) {
    float s = sum[r];
#pragma unroll
    for (int off = 8; off; off >>= 1) s += __shfl_xor(s, off, 64);
    sum[r] = 1.0f / s;
  }
  // write fp32 probs (required output) + bf16 P into swizzled LDS
  float* Pr = probs + ((long)bh * 512 + q0 + w * 16 + quad * 4) * 512 + lr;
  const int mbase = w * 16 + quad * 4;
#pragma unroll
  for (int nt = 0; nt < 32; nt++)
#pragma unroll
    for (int r = 0; r < 4; r++) {
      float p = acc[nt][r] * sum[r];
      Pr[(long)r * 512 + nt * 16] = p;
      int m = mbase + r;
      int byte = m * 1024 + (((lr + nt * 16) * 2) ^ (((m ^ (m >> 3)) & 7) << 4));
      *(unsigned short*)((char*)P + byte) = f2bf(p);
    }
  __syncthreads();

  // ---- phase 3: PV ----
  f32x4 o[4];
#pragma unroll
  for (int dt = 0; dt < 4; dt++) o[dt] = (f32x4){0.f, 0.f, 0.f, 0.f};
  const int mrow = w * 16 + lr;
  const int swz = ((mrow ^ (mrow >> 3)) & 7) << 4;
#pragma unroll
  for (int ks = 0; ks < 16; ks++) {
    bf16x8 pa = *(const bf16x8*)((char*)P + mrow * 1024 + ((quad * 16 + ks * 64) ^ swz));
#pragma unroll
    for (int dt = 0; dt < 4; dt++) {
      bf16x8 vb = *(const bf16x8*)(Vb + (long)(dt * 16 + lr) * 512 + quad * 8 + ks * 32);
      o[dt] = __builtin_amdgcn_mfma_f32_16x16x32_bf16(pa, vb, o[dt], 0, 0, 0);
    }
  }
  const int b = bh / 12, h = bh - b * 12;
  unsigned short* So = sa + ((long)(b * 512 + q0 + w * 16 + quad * 4)) * 768 + h * 64;
#pragma unroll
  for (int dt = 0; dt < 4; dt++)
#pragma unroll
    for (int r = 0; r < 4; r++)
      So[(long)r * 768 + dt * 16 + lr] = f2bf(o[dt][r]);
}

extern "C" void kernel_launch(void* const* d_in, const int* in_sizes, int n_in,
                              void* d_out, int out_size, void* d_ws, size_t ws_size,
                              hipStream_t stream) {
  const float* x     = (const float*)d_in[0];
  const float* Wqkv  = (const float*)d_in[1];
  const float* bqkv  = (const float*)d_in[2];
  const float* Wph   = (const float*)d_in[3];
  const float* bph   = (const float*)d_in[4];
  const float* Wproj = (const float*)d_in[5];
  const float* bproj = (const float*)d_in[6];
  float* out = (float*)d_out;
  float* probs = out + 12582912L;  // [32,12,512,512]

  char* ws = (char*)d_ws;
  auto alloc = [&](size_t bytes) {
    char* p = ws;
    ws += (bytes + 255) & ~(size_t)255;
    return p;
  };
  unsigned short* x_b    = (unsigned short*)alloc(16384L * 768 * 2);
  unsigned short* wqkvt  = (unsigned short*)alloc(2304L * 768 * 2);
  unsigned short* wph_b  = (unsigned short*)alloc(768L * 768 * 2);
  unsigned short* wprojt = (unsigned short*)alloc(768L * 9216 * 2);
  unsigned short* wft    = (unsigned short*)alloc(768L * 768 * 2);
  float*          bfused = (float*)alloc(768 * 4);
  unsigned short* qb     = (unsigned short*)alloc(12582912L * 2);
  unsigned short* kb     = (unsigned short*)alloc(12582912L * 2);
  unsigned short* vtb    = (unsigned short*)alloc(12582912L * 2);
  unsigned short* sa     = (unsigned short*)alloc(12582912L * 2);

  hipMemsetAsync(bfused, 0, 768 * 4, stream);

  // pack/convert
  conv_f2b<<<12288, 256, 0, stream>>>(x, x_b, 12582912L);
  conv_f2b<<<576, 256, 0, stream>>>(Wph, wph_b, 589824L);
  transpose_f2b<<<dim3(6, 24, 12), 256, 0, stream>>>(Wqkv, wqkvt, 768, 192);
  transpose_f2b<<<dim3(24, 288, 1), 256, 0, stream>>>(Wproj, wprojt, 9216, 768);
  bias_fuse<<<dim3(3, 36), 256, 0, stream>>>(bph, Wproj, bproj, bfused);

  // QKV projection: [16384,768] @ [2304,768]^T, scatter epilogue (128^2 tile)
  gemm128<<<dim3(18, 128), 256, 0, stream>>>(x_b, 768, wqkvt, 768, 768,
                                             EpiQKV{bqkv, qb, kb, vtb});
  // fused attention: scores + softmax + PV (probs written once, straight to d_out)
  attn_fused<<<dim3(8, 384), 256, 0, stream>>>(qb, kb, vtb, probs, sa);
  // Wfused^T: per h: Wph_h[64,768] @ Wproj_t[:, h*768:+768]^T
  gemm_bt<<<dim3(12, 1, 12), 256, 0, stream>>>(wph_b, 49152L, 768, wprojt, 768L, 9216, 768,
                                               EpiWf{wft});
  // final: [16384,768] @ [768,768]^T + bfused -> d_out (128^2 tile)
  gemm128<<<dim3(6, 128), 256, 0, stream>>>(sa, 768, wft, 768, 768,
                                            EpiOut{out, bfused});
}

// Round 4
// 840.409 us; speedup vs baseline: 1.1408x; 1.0728x over previous
//
#include <hip/hip_runtime.h>
#include <stdint.h>

typedef float f32x4 __attribute__((ext_vector_type(4)));
typedef short bf16x8 __attribute__((ext_vector_type(8)));

__device__ __forceinline__ unsigned short f2bf(float f) {
  union { float f; uint32_t u; } v; v.f = f;
  uint32_t r = v.u + 0x7FFFu + ((v.u >> 16) & 1u);
  return (unsigned short)(r >> 16);
}

// async global->LDS, 16B per lane. LDS dest is wave-uniform base + lane*16.
__device__ __forceinline__ void gload16(const unsigned short* g, unsigned short* l) {
  __builtin_amdgcn_global_load_lds(
      (const __attribute__((address_space(1))) void*)g,
      (__attribute__((address_space(3))) void*)l, 16, 0, 0);
}

// ---------- elementwise fp32 -> bf16 ----------
__global__ __launch_bounds__(256) void conv_f2b(const float* __restrict__ in,
                                                unsigned short* __restrict__ out, long n) {
  long i = ((long)blockIdx.x * 256 + threadIdx.x) * 4;
  if (i + 3 < n) {
    float4 f = *(const float4*)(in + i);
    ushort4 o;
    o.x = f2bf(f.x); o.y = f2bf(f.y); o.z = f2bf(f.z); o.w = f2bf(f.w);
    *(ushort4*)(out + i) = o;
  }
}

// ---------- batched tiled transpose fp32 [R,C] -> bf16 [C,R] ----------
__global__ __launch_bounds__(256) void transpose_f2b(const float* __restrict__ in,
                                                     unsigned short* __restrict__ out,
                                                     int R, int C) {
  __shared__ unsigned short tile[32][33];
  long base = (long)blockIdx.z * R * C;
  in += base; out += base;
  int c0 = blockIdx.x * 32, r0 = blockIdx.y * 32;
  int tx = threadIdx.x & 31, ty = threadIdx.x >> 5;  // ty: 0..7
#pragma unroll
  for (int i = 0; i < 32; i += 8)
    tile[ty + i][tx] = f2bf(in[(long)(r0 + ty + i) * C + c0 + tx]);
  __syncthreads();
#pragma unroll
  for (int i = 0; i < 32; i += 8)
    out[(long)(c0 + ty + i) * R + r0 + tx] = tile[tx][ty + i];
}

// ---------- Wqkv transpose, routed: [H,768,192] fp32 -> wqkt[1536,768] + wvt[768,768] --
// wqkt row (h*128 + d2) = Wqkv[h,:,d2] for d2<128 (q:0-63, k:64-127)
// wvt  row (h*64 + d)   = Wqkv[h,:,128+d]
__global__ __launch_bounds__(256) void transpose_wqkv(const float* __restrict__ in,
                                                      unsigned short* __restrict__ wqkt,
                                                      unsigned short* __restrict__ wvt) {
  __shared__ unsigned short tile[32][33];
  int h = blockIdx.z;
  const float* src = in + (long)h * 768 * 192;
  int c0 = blockIdx.x * 32;  // d3 (0..191)
  int r0 = blockIdx.y * 32;  // channel (0..767)
  int tx = threadIdx.x & 31, ty = threadIdx.x >> 5;
#pragma unroll
  for (int i = 0; i < 32; i += 8)
    tile[ty + i][tx] = f2bf(src[(long)(r0 + ty + i) * 192 + c0 + tx]);
  __syncthreads();
#pragma unroll
  for (int i = 0; i < 32; i += 8) {
    int d3 = c0 + ty + i, ch = r0 + tx;
    if (d3 < 128) wqkt[(long)(h * 128 + d3) * 768 + ch] = tile[tx][ty + i];
    else          wvt[(long)(h * 64 + (d3 - 128)) * 768 + ch] = tile[tx][ty + i];
  }
}

// ---------- fused bias: bfused[j] = sum_r bph_flat[r]*Wproj[r,j] + bproj[j] ----------
__global__ __launch_bounds__(256) void bias_fuse(const float* __restrict__ bph,
                                                 const float* __restrict__ Wproj,
                                                 const float* __restrict__ bproj,
                                                 float* __restrict__ bfused) {
  int j = blockIdx.x * 256 + threadIdx.x;  // < 768
  int r0 = blockIdx.y * 256;
  float acc = 0.f;
  for (int r = r0; r < r0 + 256; r++)
    acc += bph[r] * Wproj[(long)r * 768 + j];
  if (blockIdx.y == 0) acc += bproj[j];
  atomicAdd(&bfused[j], acc);
}

// ---------- staging helpers (8 elements -> bf16 LDS) ----------
__device__ __forceinline__ void stage8(const unsigned short* __restrict__ g,
                                       unsigned short* __restrict__ s) {
  *(uint4*)s = *(const uint4*)g;
}

// ---------- generic 64x64-tile MFMA GEMM (small shapes) ----------
template <typename AT, typename Epi>
__global__ __launch_bounds__(256) void gemm_bt(const AT* __restrict__ A, long asb, int lda,
                                               const unsigned short* __restrict__ Bt, long bsb,
                                               int ldb, int K, Epi epi) {
  __shared__ __align__(16) unsigned short As[64][32];
  __shared__ __align__(16) unsigned short Bs[64][32];
  const int tid = threadIdx.x;
  const int row = tid >> 2;
  const int kc = (tid & 3) * 8;
  const int lane = tid & 63;
  const int w = tid >> 6;
  const int quad = lane >> 4, lr = lane & 15;
  const int bz = blockIdx.z;

  f32x4 acc[4];
#pragma unroll
  for (int i = 0; i < 4; i++) acc[i] = (f32x4){0.f, 0.f, 0.f, 0.f};

  const AT* Ab = A + (long)bz * asb + (long)(blockIdx.y * 64 + row) * lda;
  const unsigned short* Bb = Bt + (long)bz * bsb + (long)(blockIdx.x * 64 + row) * ldb;

  for (int k0 = 0; k0 < K; k0 += 32) {
    stage8(Ab + k0 + kc, &As[row][kc]);
    stage8(Bb + k0 + kc, &Bs[row][kc]);
    __syncthreads();
    bf16x8 a = *(const bf16x8*)&As[w * 16 + lr][quad * 8];
#pragma unroll
    for (int nt = 0; nt < 4; nt++) {
      bf16x8 b = *(const bf16x8*)&Bs[nt * 16 + lr][quad * 8];
      acc[nt] = __builtin_amdgcn_mfma_f32_16x16x32_bf16(a, b, acc[nt], 0, 0, 0);
    }
    __syncthreads();
  }
  const int mg = blockIdx.y * 64 + w * 16 + quad * 4;
  const int ng = blockIdx.x * 64 + lr;
#pragma unroll
  for (int nt = 0; nt < 4; nt++)
#pragma unroll
    for (int r = 0; r < 4; r++)
      epi(bz, mg + r, ng + nt * 16, acc[nt][r]);
}

// ---------- 128x128-tile MFMA GEMM (batched): C = A[M,K] @ Bt[N,K]^T ----------
template <typename Epi>
__global__ __launch_bounds__(256) void gemm128(const unsigned short* __restrict__ A, long asb,
                                               int lda, const unsigned short* __restrict__ Bt,
                                               long bsb, int ldb, int K, Epi epi) {
  __shared__ __align__(16) unsigned short As[128][32];
  __shared__ __align__(16) unsigned short Bs[128][32];
  const int tid = threadIdx.x;
  const int lane = tid & 63;
  const int w = tid >> 6;
  const int quad = lane >> 4, lr = lane & 15;
  const int sr = lane >> 2;
  const int sc = (lane & 3) * 8;
  const int bz = blockIdx.z;

  f32x4 acc[4][4];
#pragma unroll
  for (int i = 0; i < 4; i++)
#pragma unroll
    for (int j = 0; j < 4; j++) acc[i][j] = (f32x4){0.f, 0.f, 0.f, 0.f};

  const unsigned short* Ag = A + (long)bz * asb + (long)(blockIdx.y * 128 + w * 16 + sr) * lda + sc;
  const unsigned short* Bg = Bt + (long)bz * bsb + (long)(blockIdx.x * 128 + w * 16 + sr) * ldb + sc;
  unsigned short* Al0 = &As[w * 16][0];
  unsigned short* Al1 = &As[64 + w * 16][0];
  unsigned short* Bl0 = &Bs[w * 16][0];
  unsigned short* Bl1 = &Bs[64 + w * 16][0];
  const int wr = (w >> 1) * 64, wc = (w & 1) * 64;

  for (int k0 = 0; k0 < K; k0 += 32) {
    gload16(Ag + k0, Al0);
    gload16(Ag + k0 + (long)64 * lda, Al1);
    gload16(Bg + k0, Bl0);
    gload16(Bg + k0 + (long)64 * ldb, Bl1);
    __syncthreads();
    bf16x8 a[4], b[4];
#pragma unroll
    for (int mt = 0; mt < 4; mt++) a[mt] = *(const bf16x8*)&As[wr + mt * 16 + lr][quad * 8];
#pragma unroll
    for (int nt = 0; nt < 4; nt++) b[nt] = *(const bf16x8*)&Bs[wc + nt * 16 + lr][quad * 8];
#pragma unroll
    for (int mt = 0; mt < 4; mt++)
#pragma unroll
      for (int nt = 0; nt < 4; nt++)
        acc[mt][nt] = __builtin_amdgcn_mfma_f32_16x16x32_bf16(a[mt], b[nt], acc[mt][nt], 0, 0, 0);
    __syncthreads();
  }
  const int mg0 = blockIdx.y * 128 + wr + quad * 4;
  const int ng0 = blockIdx.x * 128 + wc + lr;
#pragma unroll
  for (int mt = 0; mt < 4; mt++)
#pragma unroll
    for (int nt = 0; nt < 4; nt++)
#pragma unroll
      for (int r = 0; r < 4; r++)
        epi(bz, mg0 + mt * 16 + r, ng0 + nt * 16, acc[mt][nt][r]);
}

// ---------- epilogues ----------
struct EpiQK {  // n = h*128 + d2 (q: d2<64, k: d2-64); coalesced d-contiguous stores
  const float* bqkv;
  unsigned short *q, *k;
  __device__ void operator()(int, int m, int n, float val) const {
    int h = n >> 7, d2 = n & 127;
    unsigned short bv = f2bf(val + bqkv[h * 192 + d2]);
    int b = m >> 9, t = m & 511;
    long base = ((long)(b * 12 + h) * 512 + t) * 64;
    if (d2 < 64) q[base + d2] = bv;
    else         k[base + d2 - 64] = bv;
  }
};
struct EpiVt {  // transposed V-gemm: z=b, m=(h,d), n=t; vt row-major -> coalesced over t
  const float* bqkv;
  unsigned short* vt;
  __device__ void operator()(int z, int m, int n, float val) const {
    vt[((long)z * 768 + m) * 512 + n] = f2bf(val + bqkv[(m >> 6) * 192 + 128 + (m & 63)]);
  }
};
struct EpiWf {  // Wfused^T bf16 [768 j, 768 hd]; z = h, m = d
  unsigned short* wft;
  __device__ void operator()(int z, int m, int n, float val) const {
    wft[(long)n * 768 + z * 64 + m] = f2bf(val);
  }
};
struct EpiOut {  // final fp32 output + fused bias
  float* out;
  const float* bfused;
  __device__ void operator()(int, int m, int n, float val) const {
    out[(long)m * 768 + n] = val + bfused[n];
  }
};

// ---------- fused attention: scores + softmax + PV, one (b,h) x 64-row q-tile / block ----
__global__ __launch_bounds__(256, 2) void attn_fused(
    const unsigned short* __restrict__ q,   // [BH,512,64] bf16
    const unsigned short* __restrict__ k,   // [BH,512,64] bf16
    const unsigned short* __restrict__ vt,  // [BH,64,512] bf16
    float* __restrict__ probs,              // [BH,512,512] fp32 (d_out region)
    unsigned short* __restrict__ sa)        // [B*T,768] bf16
{
  __shared__ __align__(16) unsigned short P[64][512];  // 64 KB, swizzled
  const int tid = threadIdx.x;
  const int w = tid >> 6;
  const int lane = tid & 63;
  const int quad = lane >> 4, lr = lane & 15;
  const int bh = blockIdx.y;
  const int q0 = blockIdx.x * 64;

  const unsigned short* Qb = q + ((long)bh * 512 + q0 + w * 16) * 64;
  const unsigned short* Kb = k + (long)bh * 512 * 64;
  const unsigned short* Vb = vt + (long)bh * 64 * 512;

  // ---- phase 1: scores ----
  bf16x8 a0 = *(const bf16x8*)(Qb + (long)lr * 64 + quad * 8);
  bf16x8 a1 = *(const bf16x8*)(Qb + (long)lr * 64 + quad * 8 + 32);
  f32x4 acc[32];
#pragma unroll
  for (int nt = 0; nt < 32; nt++) acc[nt] = (f32x4){0.f, 0.f, 0.f, 0.f};
#pragma unroll
  for (int nt = 0; nt < 32; nt++) {
    const unsigned short* kr = Kb + (long)(nt * 16 + lr) * 64 + quad * 8;
    bf16x8 b0 = *(const bf16x8*)kr;
    bf16x8 b1 = *(const bf16x8*)(kr + 32);
    acc[nt] = __builtin_amdgcn_mfma_f32_16x16x32_bf16(a0, b0, acc[nt], 0, 0, 0);
    acc[nt] = __builtin_amdgcn_mfma_f32_16x16x32_bf16(a1, b1, acc[nt], 0, 0, 0);
  }

  // ---- phase 2: softmax (cols live in the 16 lanes of this quad) ----
  float mx[4], sum[4];
#pragma unroll
  for (int r = 0; r < 4; r++) {
    float m = -1e30f;
#pragma unroll
    for (int nt = 0; nt < 32; nt++) m = fmaxf(m, acc[nt][r]);
#pragma unroll
    for (int off = 8; off; off >>= 1) m = fmaxf(m, __shfl_xor(m, off, 64));
    mx[r] = m;
    sum[r] = 0.f;
  }
#pragma unroll
  for (int nt = 0; nt < 32; nt++)
#pragma unroll
    for (int r = 0; r < 4; r++) {
      float p = __expf(0.125f * (acc[nt][r] - mx[r]));
      acc[nt][r] = p;
      sum[r] += p;
    }
#pragma unroll
  for (int r = 0; r < 4; r++) {
    float s = sum[r];
#pragma unroll
    for (int off = 8; off; off >>= 1) s += __shfl_xor(s, off, 64);
    sum[r] = 1.0f / s;
  }
  // write fp32 probs (nt: streaming, never re-read) + bf16 P into swizzled LDS
  float* Pr = probs + ((long)bh * 512 + q0 + w * 16 + quad * 4) * 512 + lr;
  const int mbase = w * 16 + quad * 4;
#pragma unroll
  for (int nt = 0; nt < 32; nt++)
#pragma unroll
    for (int r = 0; r < 4; r++) {
      float p = acc[nt][r] * sum[r];
      __builtin_nontemporal_store(p, Pr + (long)r * 512 + nt * 16);
      int m = mbase + r;
      int byte = m * 1024 + (((lr + nt * 16) * 2) ^ (((m ^ (m >> 3)) & 7) << 4));
      *(unsigned short*)((char*)P + byte) = f2bf(p);
    }
  __syncthreads();

  // ---- phase 3: PV ----
  f32x4 o[4];
#pragma unroll
  for (int dt = 0; dt < 4; dt++) o[dt] = (f32x4){0.f, 0.f, 0.f, 0.f};
  const int mrow = w * 16 + lr;
  const int swz = ((mrow ^ (mrow >> 3)) & 7) << 4;
#pragma unroll
  for (int ks = 0; ks < 16; ks++) {
    bf16x8 pa = *(const bf16x8*)((char*)P + mrow * 1024 + ((quad * 16 + ks * 64) ^ swz));
#pragma unroll
    for (int dt = 0; dt < 4; dt++) {
      bf16x8 vb = *(const bf16x8*)(Vb + (long)(dt * 16 + lr) * 512 + quad * 8 + ks * 32);
      o[dt] = __builtin_amdgcn_mfma_f32_16x16x32_bf16(pa, vb, o[dt], 0, 0, 0);
    }
  }
  const int b = bh / 12, h = bh - b * 12;
  unsigned short* So = sa + ((long)(b * 512 + q0 + w * 16 + quad * 4)) * 768 + h * 64;
#pragma unroll
  for (int dt = 0; dt < 4; dt++)
#pragma unroll
    for (int r = 0; r < 4; r++)
      So[(long)r * 768 + dt * 16 + lr] = f2bf(o[dt][r]);
}

extern "C" void kernel_launch(void* const* d_in, const int* in_sizes, int n_in,
                              void* d_out, int out_size, void* d_ws, size_t ws_size,
                              hipStream_t stream) {
  const float* x     = (const float*)d_in[0];
  const float* Wqkv  = (const float*)d_in[1];
  const float* bqkv  = (const float*)d_in[2];
  const float* Wph   = (const float*)d_in[3];
  const float* bph   = (const float*)d_in[4];
  const float* Wproj = (const float*)d_in[5];
  const float* bproj = (const float*)d_in[6];
  float* out = (float*)d_out;
  float* probs = out + 12582912L;  // [32,12,512,512]

  char* ws = (char*)d_ws;
  auto alloc = [&](size_t bytes) {
    char* p = ws;
    ws += (bytes + 255) & ~(size_t)255;
    return p;
  };
  unsigned short* x_b    = (unsigned short*)alloc(16384L * 768 * 2);
  unsigned short* wqkt   = (unsigned short*)alloc(1536L * 768 * 2);
  unsigned short* wvt    = (unsigned short*)alloc(768L * 768 * 2);
  unsigned short* wph_b  = (unsigned short*)alloc(768L * 768 * 2);
  unsigned short* wprojt = (unsigned short*)alloc(768L * 9216 * 2);
  unsigned short* wft    = (unsigned short*)alloc(768L * 768 * 2);
  float*          bfused = (float*)alloc(768 * 4);
  unsigned short* qb     = (unsigned short*)alloc(12582912L * 2);
  unsigned short* kb     = (unsigned short*)alloc(12582912L * 2);
  unsigned short* vtb    = (unsigned short*)alloc(12582912L * 2);
  unsigned short* sa     = (unsigned short*)alloc(12582912L * 2);

  hipMemsetAsync(bfused, 0, 768 * 4, stream);

  // pack/convert
  conv_f2b<<<12288, 256, 0, stream>>>(x, x_b, 12582912L);
  conv_f2b<<<576, 256, 0, stream>>>(Wph, wph_b, 589824L);
  transpose_wqkv<<<dim3(6, 24, 12), 256, 0, stream>>>(Wqkv, wqkt, wvt);
  transpose_f2b<<<dim3(24, 288, 1), 256, 0, stream>>>(Wproj, wprojt, 9216, 768);
  bias_fuse<<<dim3(3, 36), 256, 0, stream>>>(bph, Wproj, bproj, bfused);

  // QK projection: [16384,768] @ [1536,768]^T, coalesced q/k epilogue (128^2 tile)
  gemm128<<<dim3(12, 128, 1), 256, 0, stream>>>(x_b, 0L, 768, wqkt, 0L, 768, 768,
                                                EpiQK{bqkv, qb, kb});
  // V^T (transposed gemm, batched over b): wvt[768,768] @ x_b[b][512,768]^T -> vt rows (h,d)
  gemm128<<<dim3(4, 6, 32), 256, 0, stream>>>(wvt, 0L, 768, x_b, 512L * 768, 768, 768,
                                              EpiVt{bqkv, vtb});
  // fused attention: scores + softmax + PV (probs written once, nt, straight to d_out)
  attn_fused<<<dim3(8, 384), 256, 0, stream>>>(qb, kb, vtb, probs, sa);
  // Wfused^T: per h: Wph_h[64,768] @ Wproj_t[:, h*768:+768]^T
  gemm_bt<<<dim3(12, 1, 12), 256, 0, stream>>>(wph_b, 49152L, 768, wprojt, 768L, 9216, 768,
                                               EpiWf{wft});
  // final: [16384,768] @ [768,768]^T + bfused -> d_out (128^2 tile)
  gemm128<<<dim3(6, 128, 1), 256, 0, stream>>>(sa, 0L, 768, wft, 0L, 768, 768,
                                               EpiOut{out, bfused});
}